// Round 14
// baseline (536.289 us; speedup 1.0000x reference)
//
#include <hip/hip_runtime.h>
#include <math.h>

#define DD 128    // node / hidden dim
#define FF 64     // edge feature dim
#define BM 64     // edges per tile
#define SENT 0xFFFFFFFFu

typedef __attribute__((ext_vector_type(8))) short bf16x8;
typedef __attribute__((ext_vector_type(4))) short short4s;
typedef __attribute__((ext_vector_type(4))) float f32x4;

__device__ __forceinline__ float ssp_f(float x) {
    float ax = fabsf(x);
    float e  = __expf(-ax);
    return fmaxf(x, 0.0f) + __logf(1.0f + e) - 0.6931471805599453f;
}

__device__ __forceinline__ unsigned short f2bf(float f) {
    unsigned u = __float_as_uint(f);
    unsigned r = (u + 0x7FFFu + ((u >> 16) & 1u)) >> 16;
    return (unsigned short)r;
}
__device__ __forceinline__ float bf2f(unsigned short h) {
    return __uint_as_float(((unsigned)h) << 16);
}

__global__ void copy_nodes_kernel(const float4* __restrict__ src,
                                  float4* __restrict__ dst, int n4) {
    int i = blockIdx.x * blockDim.x + threadIdx.x;
    int stride = gridDim.x * blockDim.x;
    for (; i < n4; i += stride) dst[i] = src[i];
}

__global__ void zero_u32_kernel(unsigned* __restrict__ p, int n) {
    int i = blockIdx.x * blockDim.x + threadIdx.x;
    int stride = gridDim.x * blockDim.x;
    for (; i < n; i += stride) p[i] = 0u;
}

__global__ void hist_kernel(const int* __restrict__ eidx,
                            unsigned* __restrict__ counts, int E) {
    int e = blockIdx.x * blockDim.x + threadIdx.x;
    if (e < E) atomicAdd(&counts[eidx[2 * e]], 1u);
}

__global__ void scan1_kernel(const unsigned* __restrict__ counts,
                             unsigned* __restrict__ cursor,
                             unsigned* __restrict__ bsums, int n) {
    __shared__ unsigned s[256];
    int i = blockIdx.x * 256 + threadIdx.x;
    unsigned v = (i < n) ? counts[i] : 0u;
    s[threadIdx.x] = v;
    __syncthreads();
    #pragma unroll
    for (int d = 1; d < 256; d <<= 1) {
        unsigned t = (threadIdx.x >= d) ? s[threadIdx.x - d] : 0u;
        __syncthreads();
        s[threadIdx.x] += t;
        __syncthreads();
    }
    if (i < n) cursor[i] = s[threadIdx.x] - v;
    if (threadIdx.x == 255) bsums[blockIdx.x] = s[255];
}

__global__ void scan2_kernel(unsigned* __restrict__ bsums, int nb) {
    __shared__ unsigned s[512];
    int t = threadIdx.x;
    if (nb <= 512) {
        unsigned v = (t < nb) ? bsums[t] : 0u;
        s[t] = v;
        __syncthreads();
        #pragma unroll
        for (int d = 1; d < 512; d <<= 1) {
            unsigned x = (t >= d) ? s[t - d] : 0u;
            __syncthreads();
            s[t] += x;
            __syncthreads();
        }
        if (t < nb) bsums[t] = s[t] - v;
    } else if (t == 0) {
        unsigned run = 0u;
        for (int i = 0; i < nb; ++i) { unsigned x = bsums[i]; bsums[i] = run; run += x; }
    }
}

__global__ void scan3_kernel(unsigned* __restrict__ cursor,
                             const unsigned* __restrict__ bsums, int n) {
    int i = blockIdx.x * 256 + threadIdx.x;
    if (i < n) cursor[i] += bsums[blockIdx.x];
}

// ---- scatter_move: natural-order STREAMING read of edges, fp32->bf16 hi,
// tile-XOR-swizzle, SCATTERED write of 128B row to sorted position ----
__global__ void scatter_move_kernel(const int* __restrict__ eidx,
                                    const float* __restrict__ edges,
                                    unsigned* __restrict__ cursor,
                                    unsigned short* __restrict__ edgesS,
                                    unsigned* __restrict__ sorted_nt,
                                    unsigned* __restrict__ sorted_ns, int E) {
    int e = blockIdx.x * blockDim.x + threadIdx.x;
    if (e >= E) return;
    int ns = eidx[2 * e];
    unsigned pos = atomicAdd(&cursor[ns], 1u);
    sorted_nt[pos] = (unsigned)eidx[2 * e + 1];
    sorted_ns[pos] = (unsigned)ns;

    int r = (int)(pos & 63);                         // row within its tile
    unsigned short* drow = edgesS + (size_t)pos * FF;
    const float4* src = reinterpret_cast<const float4*>(edges) + (size_t)e * 16;
    #pragma unroll
    for (int q = 0; q < 16; ++q) {                   // 16 x float4 = 64 floats
        float4 v = src[q];
        short4s hv = { (short)f2bf(v.x), (short)f2bf(v.y),
                       (short)f2bf(v.z), (short)f2bf(v.w) };
        int g = q >> 1, half = q & 1;
        *reinterpret_cast<short4s*>(drow + ((g ^ (r & 7)) * 8) + half * 4) = hv;
    }
}

// ---- prep: split W[K][128] into bf16 hi/lo, MFMA B-fragment order ----
__global__ void prep_w_kernel(const float* __restrict__ W, int K,
                              unsigned short* __restrict__ hi,
                              unsigned short* __restrict__ lo) {
    int S = K >> 5;
    int idx = blockIdx.x * blockDim.x + threadIdx.x;
    int total = 8 * S * 64;
    if (idx >= total) return;
    int l = idx & 63;
    int s = (idx >> 6) % S;
    int j = idx / (64 * S);
    int col = j * 16 + (l & 15);
    int kbase = s * 32 + (l >> 4) * 8;
    int ob = ((j * S + s) * 64 + l) * 8;
    #pragma unroll
    for (int i = 0; i < 8; ++i) {
        float w = W[(size_t)(kbase + i) * DD + col];
        unsigned short h = f2bf(w);
        hi[ob + i] = h;
        lo[ob + i] = f2bf(w - bf2f(h));
    }
}

// ---- phase 2: fused GEMM1+GEMM2+multiply+bitmask reduce, 16KB LDS ----
// region lifetimes: A_hi(8K) -> F1_hi(16K) -> SM f32 col-half(16K) x2
__launch_bounds__(256, 5)
__global__ void edge_mfma_kernel(const float* __restrict__ nodes,
                                 const unsigned short* __restrict__ edgesS,
                                 const unsigned* __restrict__ sorted_nt,
                                 const unsigned* __restrict__ sorted_ns,
                                 const unsigned* __restrict__ ends,
                                 const unsigned short* __restrict__ W1h,
                                 const unsigned short* __restrict__ W1l,
                                 const unsigned short* __restrict__ W2h,
                                 const unsigned short* __restrict__ W2l,
                                 const float* __restrict__ b1,
                                 const float* __restrict__ b2,
                                 float* __restrict__ out,
                                 float* __restrict__ bpart,
                                 unsigned* __restrict__ bnode,
                                 int E) {
    __shared__ unsigned short region[8192];      // 16 KB, aliased
    __shared__ float comm[64];                   // mid-boundary partial handoff
    float* SM = reinterpret_cast<float*>(region);   // 64x64 f32 column-half

    const int t = threadIdx.x;
    const int tlo = blockIdx.x * BM;

    // per-lane start-node ids (every wave holds ns[0..63] across its lanes)
    unsigned ns_reg = (tlo + (t & 63) < E) ? sorted_ns[tlo + (t & 63)] : SENT;

    // ---- stage A: straight copy of pre-swizzled bf16 tile (8KB) ----
    {
        const bf16x8* src = reinterpret_cast<const bf16x8*>(edgesS + (size_t)tlo * FF);
        bf16x8* dst = reinterpret_cast<bf16x8*>(region);
        dst[t]       = src[t];
        dst[256 + t] = src[256 + t];
    }
    __syncthreads();   // B1: A visible

    const int lane = t & 63, wave = t >> 6;
    const int wrow = wave * 16;
    const int lr = lane & 15, lg = lane >> 4;
    const f32x4 zero4 = { 0.f, 0.f, 0.f, 0.f };

    // ---- GEMM1 A-fragments ----
    bf16x8 a1[2];
    #pragma unroll
    for (int s = 0; s < 2; ++s) {
        int row = wrow + lr;
        a1[s] = *reinterpret_cast<const bf16x8*>(
            region + row * FF + (((s * 4 + lg) ^ (row & 7)) * 8));
    }
    __syncthreads();   // B2: A reads done -> F1 may overwrite region

    // ---- GEMM1: A_hi x (W1h + W1l), W from L2, loads grouped per j ----
    f32x4 acc1[8];
    #pragma unroll
    for (int j = 0; j < 8; ++j) acc1[j] = zero4;
    #pragma unroll
    for (int j = 0; j < 8; ++j) {
        bf16x8 wh[2], wl[2];
        #pragma unroll
        for (int s = 0; s < 2; ++s) {
            wh[s] = *reinterpret_cast<const bf16x8*>(W1h + ((size_t)((j * 2 + s) * 64 + lane)) * 8);
            wl[s] = *reinterpret_cast<const bf16x8*>(W1l + ((size_t)((j * 2 + s) * 64 + lane)) * 8);
        }
        #pragma unroll
        for (int s = 0; s < 2; ++s) {
            acc1[j] = __builtin_amdgcn_mfma_f32_16x16x32_bf16(a1[s], wh[s], acc1[j], 0, 0, 0);
            acc1[j] = __builtin_amdgcn_mfma_f32_16x16x32_bf16(a1[s], wl[s], acc1[j], 0, 0, 0);
        }
    }

    // ---- epilogue1: bias + ssp -> F1 hi (full 16KB region), &15 swizzle ----
    #pragma unroll
    for (int j = 0; j < 8; ++j) {
        int col = j * 16 + lr;
        float bv = b1[col];
        int gc = col >> 3, ci = col & 7;
        #pragma unroll
        for (int r = 0; r < 4; ++r) {
            int row = wrow + lg * 4 + r;
            region[row * DD + ((gc ^ (row & 15)) * 8 + ci)] =
                f2bf(ssp_f(acc1[j][r] + bv));
        }
    }
    __syncthreads();   // B3: F1 visible

    // ---- GEMM2 A-fragments from F1 (live across both column halves) ----
    bf16x8 a2[4];
    #pragma unroll
    for (int s = 0; s < 4; ++s) {
        int row = wrow + lr;
        a2[s] = *reinterpret_cast<const bf16x8*>(
            region + row * DD + (((s * 4 + lg) ^ (row & 15)) * 8));
    }
    __syncthreads();   // B4: F1 reads done -> SM may overwrite region

    // ---- wave-uniform reduce bookkeeping (computed once) ----
    int pl = (lane == 0) ? 0 : lane - 1;
    unsigned prevns = __shfl(ns_reg, pl);
    unsigned long long bnd = __ballot((lane > 0) && (ns_reg != prevns));
    unsigned n0  = __shfl(ns_reg, 0);
    unsigned n31 = __shfl(ns_reg, 31);
    unsigned n32 = __shfl(ns_reg, 32);
    bool cont_mid = (n31 == n32) && (n31 != SENT);
    unsigned s0 = (n0 == 0u) ? 0u : ends[n0 - 1];
    bool contFirst = (s0 < (unsigned)tlo);
    bool spans0 = (n0 == n31);

    const float4* n4p = reinterpret_cast<const float4*>(nodes);

    #pragma unroll 1
    for (int h = 0; h < 2; ++h) {
        // ---- issue gathered node-row loads for this column half ----
        float4 nv[4];
        #pragma unroll
        for (int it = 0; it < 4; ++it) {
            int idx = it * 256 + t;
            int row = idx >> 4, c4 = idx & 15;
            unsigned nt_ = (tlo + row < E) ? sorted_nt[tlo + row] : 0u;
            nv[it] = n4p[(size_t)nt_ * 32 + h * 16 + c4];
        }

        // ---- GEMM2 half: j in [h*4, h*4+4) ----
        f32x4 acc2[4];
        #pragma unroll
        for (int jj = 0; jj < 4; ++jj) acc2[jj] = zero4;
        #pragma unroll
        for (int jj = 0; jj < 4; ++jj) {
            int j = h * 4 + jj;
            bf16x8 wh[4], wl[4];
            #pragma unroll
            for (int s = 0; s < 4; ++s) {
                wh[s] = *reinterpret_cast<const bf16x8*>(W2h + ((size_t)((j * 4 + s) * 64 + lane)) * 8);
                wl[s] = *reinterpret_cast<const bf16x8*>(W2l + ((size_t)((j * 4 + s) * 64 + lane)) * 8);
            }
            #pragma unroll
            for (int s = 0; s < 4; ++s) {
                acc2[jj] = __builtin_amdgcn_mfma_f32_16x16x32_bf16(a2[s], wh[s], acc2[jj], 0, 0, 0);
                acc2[jj] = __builtin_amdgcn_mfma_f32_16x16x32_bf16(a2[s], wl[s], acc2[jj], 0, 0, 0);
            }
        }

        // ---- epilogue2 half: filt = ssp(acc2 + b2) -> SM (stride 64, swizzled)
        #pragma unroll
        for (int jj = 0; jj < 4; ++jj) {
            int col = (h * 4 + jj) * 16 + lr;
            float bv = b2[col];
            int colh = jj * 16 + lr;
            #pragma unroll
            for (int r = 0; r < 4; ++r) {
                int row = wrow + lg * 4 + r;
                SM[row * 64 + (colh ^ (((row >> 2) & 3) << 4))] =
                    ssp_f(acc2[jj][r] + bv);
            }
        }
        __syncthreads();   // B5: SM half ready

        // ---- multiply: SM[row] *= nodes[nt[row]] (nv in regs) ----
        #pragma unroll
        for (int it = 0; it < 4; ++it) {
            int idx = it * 256 + t;
            int row = idx >> 4, c4 = idx & 15;
            int foff = row * 64 + ((c4 * 4) ^ (((row >> 2) & 3) << 4));
            float4 mv = *reinterpret_cast<float4*>(SM + foff);
            mv.x *= nv[it].x; mv.y *= nv[it].y; mv.z *= nv[it].z; mv.w *= nv[it].w;
            *reinterpret_cast<float4*>(SM + foff) = mv;
        }
        __syncthreads();   // B6: messages (half) ready

        // ---- split-bitmask segment reduce: 128 threads = 64 cols x 2 row-halves
        float firstacc = 0.f;
        bool firstpend = false;
        if (t < 128) {
            const int y = t >> 6;            // row-half owner
            const int colh = t & 63;
            const int col = h * 64 + colh;
            const int rbeg = y * 32;

            float acc = 0.f;
            int segstart = rbeg;
            bool pend = (y == 1) && cont_mid;   // leading seg continues from lower half
            #pragma unroll 1
            for (int r = rbeg; r < rbeg + 32; ++r) {
                if (r > rbeg && ((bnd >> r) & 1ull)) {
                    unsigned node = __shfl(ns_reg, segstart);
                    if (pend) {
                        firstacc = acc; firstpend = true; pend = false;
                    } else if (node != SENT) {
                        if (segstart == 0 && contFirst)
                            bpart[(size_t)blockIdx.x * DD + col] = acc;
                        else
                            out[(size_t)node * DD + col] = nodes[(size_t)node * DD + col] + acc;
                    }
                    acc = 0.f; segstart = r;
                }
                acc += SM[r * 64 + (colh ^ (((r >> 2) & 3) << 4))];
            }
            // trailing segment of this row-half
            {
                unsigned node = __shfl(ns_reg, segstart);
                if (y == 0 && cont_mid) {
                    comm[colh] = acc;            // pass partial to upper half
                } else if (pend) {
                    firstacc = acc; firstpend = true;
                } else if (node != SENT) {
                    if (segstart == 0 && contFirst)
                        bpart[(size_t)blockIdx.x * DD + col] = acc;
                    else
                        out[(size_t)node * DD + col] = nodes[(size_t)node * DD + col] + acc;
                }
            }
            if (t == 0 && h == 0) bnode[blockIdx.x] = contFirst ? n0 : SENT;
        }
        __syncthreads();   // B7: comm visible; SM reads done (region reusable)

        // ---- combine mid-boundary segment (upper row-half threads) ----
        if (t >= 64 && t < 128 && firstpend) {
            const int colh = t & 63;
            const int col = h * 64 + colh;
            float total = comm[colh] + firstacc;
            if (spans0 && contFirst)
                bpart[(size_t)blockIdx.x * DD + col] = total;
            else
                out[(size_t)n31 * DD + col] = nodes[(size_t)n31 * DD + col] + total;
        }
        // next half's epilogue2 writes SM only after every wave passed B7 -> safe
    }
}

// ---- fixup: add cross-tile boundary partials ----
__global__ void fixup_bpart_kernel(const float* __restrict__ bpart,
                                   const unsigned* __restrict__ bnode,
                                   float* __restrict__ out, int NT) {
    int ti = blockIdx.x * 2 + (threadIdx.x >> 7);
    if (ti >= NT) return;
    unsigned n = bnode[ti];
    if (n == SENT) return;
    int c = threadIdx.x & 127;
    atomicAdd(&out[(size_t)n * DD + c], bpart[(size_t)ti * DD + c]);
}

// ---- nodes with zero out-edges: out = nodes ----
__global__ void copy_empty_kernel(const unsigned* __restrict__ counts,
                                  const float4* __restrict__ nodes4,
                                  float4* __restrict__ out4, int N) {
    int n = blockIdx.x * 8 + (threadIdx.x >> 5);
    if (n >= N) return;
    if (counts[n] != 0u) return;
    int d4 = threadIdx.x & 31;
    out4[(size_t)n * 32 + d4] = nodes4[(size_t)n * 32 + d4];
}

// ---- fallback: fused atomic kernel (used only if ws too small) ----
__launch_bounds__(256, 2)
__global__ void edge_fused_atomic_kernel(const float* __restrict__ nodes,
                                         const float* __restrict__ edges,
                                         const int*   __restrict__ eidx,
                                         const float* __restrict__ W1,
                                         const float* __restrict__ b1,
                                         const float* __restrict__ W2,
                                         const float* __restrict__ b2,
                                         float* __restrict__ out, int E) {
    int e = blockIdx.x * 256 + threadIdx.x;
    if (e >= E) return;
    int ns = eidx[2 * e + 0];
    int nt = eidx[2 * e + 1];

    float h1[DD];
    #pragma unroll
    for (int d = 0; d < DD; ++d) h1[d] = b1[d];
    const float4* ev4 = reinterpret_cast<const float4*>(edges) + (size_t)e * (FF / 4);
    #pragma unroll 1
    for (int f4 = 0; f4 < FF / 4; ++f4) {
        float4 ev = ev4[f4];
        const float* w0 = W1 + (size_t)(f4 * 4) * DD;
        #pragma unroll
        for (int d = 0; d < DD; ++d) h1[d] = fmaf(ev.x, w0[d], h1[d]);
        #pragma unroll
        for (int d = 0; d < DD; ++d) h1[d] = fmaf(ev.y, w0[DD + d], h1[d]);
        #pragma unroll
        for (int d = 0; d < DD; ++d) h1[d] = fmaf(ev.z, w0[2 * DD + d], h1[d]);
        #pragma unroll
        for (int d = 0; d < DD; ++d) h1[d] = fmaf(ev.w, w0[3 * DD + d], h1[d]);
    }
    #pragma unroll
    for (int d = 0; d < DD; ++d) h1[d] = ssp_f(h1[d]);

    const float* nrow = nodes + (size_t)nt * DD;
    float*       orow = out   + (size_t)ns * DD;
    #pragma unroll 1
    for (int c = 0; c < 2; ++c) {
        const int base = c * 64;
        float h2[64];
        #pragma unroll
        for (int j = 0; j < 64; ++j) h2[j] = b2[base + j];
        #pragma unroll
        for (int k = 0; k < DD; ++k) {
            float hk = h1[k];
            const float* w = W2 + (size_t)k * DD + base;
            #pragma unroll
            for (int j = 0; j < 64; ++j) h2[j] = fmaf(hk, w[j], h2[j]);
        }
        #pragma unroll
        for (int j = 0; j < 64; ++j) {
            float m = ssp_f(h2[j]) * nrow[base + j];
            __hip_atomic_fetch_add(&orow[base + j], m,
                                   __ATOMIC_RELAXED, __HIP_MEMORY_SCOPE_AGENT);
        }
    }
}

extern "C" void kernel_launch(void* const* d_in, const int* in_sizes, int n_in,
                              void* d_out, int out_size, void* d_ws, size_t ws_size,
                              hipStream_t stream) {
    const float* nodes = (const float*)d_in[0];
    const float* edges = (const float*)d_in[1];
    const int*   eidx  = (const int*)  d_in[2];
    const float* W1    = (const float*)d_in[3];
    const float* b1    = (const float*)d_in[4];
    const float* W2    = (const float*)d_in[5];
    const float* b2    = (const float*)d_in[6];
    float* out = (float*)d_out;

    int ND = in_sizes[0];         // N*D
    int N  = ND / DD;             // 100000
    int E  = in_sizes[1] / FF;    // 600000
    int NT = (E + BM - 1) / BM;   // 64-row tiles

    // ---- workspace layout ----
    int nb = (N + 255) / 256;
    uintptr_t base = (uintptr_t)d_ws;
    uintptr_t p = base;
    unsigned* counts    = (unsigned*)p;  p += (size_t)N * 4;
    unsigned* cursor    = (unsigned*)p;  p += (size_t)N * 4;
    unsigned* bsums     = (unsigned*)p;  p += (size_t)nb * 4;
    unsigned* sorted_nt = (unsigned*)p;  p += (size_t)E * 4;
    unsigned* sorted_ns = (unsigned*)p;  p += (size_t)E * 4;
    p = (p + 255) & ~(uintptr_t)255;
    unsigned short* W1h = (unsigned short*)p;  p += (size_t)FF * DD * 2;
    unsigned short* W1l = (unsigned short*)p;  p += (size_t)FF * DD * 2;
    unsigned short* W2h = (unsigned short*)p;  p += (size_t)DD * DD * 2;
    unsigned short* W2l = (unsigned short*)p;  p += (size_t)DD * DD * 2;
    unsigned* bnode     = (unsigned*)p;  p += (size_t)NT * 4;
    p = (p + 255) & ~(uintptr_t)255;
    float* bpart        = (float*)p;     p += (size_t)NT * DD * 4;
    p = (p + 255) & ~(uintptr_t)255;
    unsigned short* edgesS = (unsigned short*)p;
    p += (size_t)NT * BM * FF * 2;       // pre-gathered bf16 edge tiles (~77MB)

    if ((size_t)(p - base) > ws_size) {
        copy_nodes_kernel<<<dim3(1024), dim3(256), 0, stream>>>(
            (const float4*)nodes, (float4*)out, ND / 4);
        edge_fused_atomic_kernel<<<dim3((E + 255) / 256), dim3(256), 0, stream>>>(
            nodes, edges, eidx, W1, b1, W2, b2, out, E);
        return;
    }

    // ---- prep weight fragments (bf16 split, MFMA B layout) ----
    prep_w_kernel<<<dim3(4), dim3(256), 0, stream>>>(W1, FF, W1h, W1l);
    prep_w_kernel<<<dim3(8), dim3(256), 0, stream>>>(W2, DD, W2h, W2l);

    // ---- counting sort by start node; move+convert edge rows in-pass ----
    zero_u32_kernel<<<dim3(256), dim3(256), 0, stream>>>(counts, N);
    hist_kernel<<<dim3((E + 255) / 256), dim3(256), 0, stream>>>(eidx, counts, E);
    scan1_kernel<<<dim3(nb), dim3(256), 0, stream>>>(counts, cursor, bsums, N);
    scan2_kernel<<<dim3(1), dim3(512), 0, stream>>>(bsums, nb);
    scan3_kernel<<<dim3(nb), dim3(256), 0, stream>>>(cursor, bsums, N);
    scatter_move_kernel<<<dim3((E + 255) / 256), dim3(256), 0, stream>>>(
        eidx, edges, cursor, edgesS, sorted_nt, sorted_ns, E);

    // ---- zero-edge nodes: out = nodes ----
    copy_empty_kernel<<<dim3((N + 7) / 8), dim3(256), 0, stream>>>(
        counts, (const float4*)nodes, (float4*)out, N);

    // ---- fused edge kernel (one tile per block, 16KB LDS) ----
    edge_mfma_kernel<<<dim3(NT), dim3(256), 0, stream>>>(
        nodes, edgesS, sorted_nt, sorted_ns, cursor,
        W1h, W1l, W2h, W2l, b1, b2, out, bpart, bnode, E);

    // ---- cross-tile boundary fixup ----
    fixup_bpart_kernel<<<dim3((NT + 1) / 2), dim3(256), 0, stream>>>(
        bpart, bnode, out, NT);
}

// Round 15
// 380.261 us; speedup vs baseline: 1.4103x; 1.4103x over previous
//
#include <hip/hip_runtime.h>
#include <math.h>

#define DD 128    // node / hidden dim
#define FF 64     // edge feature dim
#define BM 64     // edges per tile
#define SENT 0xFFFFFFFFu

typedef __attribute__((ext_vector_type(8))) short bf16x8;
typedef __attribute__((ext_vector_type(4))) short short4s;
typedef __attribute__((ext_vector_type(4))) float f32x4;

__device__ __forceinline__ float ssp_f(float x) {
    float ax = fabsf(x);
    float e  = __expf(-ax);
    return fmaxf(x, 0.0f) + __logf(1.0f + e) - 0.6931471805599453f;
}

__device__ __forceinline__ unsigned short f2bf(float f) {
    unsigned u = __float_as_uint(f);
    unsigned r = (u + 0x7FFFu + ((u >> 16) & 1u)) >> 16;
    return (unsigned short)r;
}
__device__ __forceinline__ float bf2f(unsigned short h) {
    return __uint_as_float(((unsigned)h) << 16);
}

__global__ void copy_nodes_kernel(const float4* __restrict__ src,
                                  float4* __restrict__ dst, int n4) {
    int i = blockIdx.x * blockDim.x + threadIdx.x;
    int stride = gridDim.x * blockDim.x;
    for (; i < n4; i += stride) dst[i] = src[i];
}

__global__ void zero_u32_kernel(unsigned* __restrict__ p, int n) {
    int i = blockIdx.x * blockDim.x + threadIdx.x;
    int stride = gridDim.x * blockDim.x;
    for (; i < n; i += stride) p[i] = 0u;
}

__global__ void hist_kernel(const int* __restrict__ eidx,
                            unsigned* __restrict__ counts, int E) {
    int e = blockIdx.x * blockDim.x + threadIdx.x;
    if (e < E) atomicAdd(&counts[eidx[2 * e]], 1u);
}

__global__ void scan1_kernel(const unsigned* __restrict__ counts,
                             unsigned* __restrict__ cursor,
                             unsigned* __restrict__ bsums, int n) {
    __shared__ unsigned s[256];
    int i = blockIdx.x * 256 + threadIdx.x;
    unsigned v = (i < n) ? counts[i] : 0u;
    s[threadIdx.x] = v;
    __syncthreads();
    #pragma unroll
    for (int d = 1; d < 256; d <<= 1) {
        unsigned t = (threadIdx.x >= d) ? s[threadIdx.x - d] : 0u;
        __syncthreads();
        s[threadIdx.x] += t;
        __syncthreads();
    }
    if (i < n) cursor[i] = s[threadIdx.x] - v;
    if (threadIdx.x == 255) bsums[blockIdx.x] = s[255];
}

__global__ void scan2_kernel(unsigned* __restrict__ bsums, int nb) {
    __shared__ unsigned s[512];
    int t = threadIdx.x;
    if (nb <= 512) {
        unsigned v = (t < nb) ? bsums[t] : 0u;
        s[t] = v;
        __syncthreads();
        #pragma unroll
        for (int d = 1; d < 512; d <<= 1) {
            unsigned x = (t >= d) ? s[t - d] : 0u;
            __syncthreads();
            s[t] += x;
            __syncthreads();
        }
        if (t < nb) bsums[t] = s[t] - v;
    } else if (t == 0) {
        unsigned run = 0u;
        for (int i = 0; i < nb; ++i) { unsigned x = bsums[i]; bsums[i] = run; run += x; }
    }
}

__global__ void scan3_kernel(unsigned* __restrict__ cursor,
                             const unsigned* __restrict__ bsums, int n) {
    int i = blockIdx.x * 256 + threadIdx.x;
    if (i < n) cursor[i] += bsums[blockIdx.x];
}

// ---- scatter_move: natural-order STREAMING read of edges, fp32->bf16 hi,
// tile-XOR-swizzle, SCATTERED write of 128B row to sorted position ----
__global__ void scatter_move_kernel(const int* __restrict__ eidx,
                                    const float* __restrict__ edges,
                                    unsigned* __restrict__ cursor,
                                    unsigned short* __restrict__ edgesS,
                                    unsigned* __restrict__ sorted_nt,
                                    unsigned* __restrict__ sorted_ns, int E) {
    int e = blockIdx.x * blockDim.x + threadIdx.x;
    if (e >= E) return;
    int ns = eidx[2 * e];
    unsigned pos = atomicAdd(&cursor[ns], 1u);
    sorted_nt[pos] = (unsigned)eidx[2 * e + 1];
    sorted_ns[pos] = (unsigned)ns;

    int r = (int)(pos & 63);                         // row within its tile
    unsigned short* drow = edgesS + (size_t)pos * FF;
    const float4* src = reinterpret_cast<const float4*>(edges) + (size_t)e * 16;
    #pragma unroll
    for (int q = 0; q < 16; ++q) {                   // 16 x float4 = 64 floats
        float4 v = src[q];
        short4s hv = { (short)f2bf(v.x), (short)f2bf(v.y),
                       (short)f2bf(v.z), (short)f2bf(v.w) };
        int g = q >> 1, half = q & 1;
        *reinterpret_cast<short4s*>(drow + ((g ^ (r & 7)) * 8) + half * 4) = hv;
    }
}

// ---- prep: split W[K][128] into bf16 hi/lo, MFMA B-fragment order ----
__global__ void prep_w_kernel(const float* __restrict__ W, int K,
                              unsigned short* __restrict__ hi,
                              unsigned short* __restrict__ lo) {
    int S = K >> 5;
    int idx = blockIdx.x * blockDim.x + threadIdx.x;
    int total = 8 * S * 64;
    if (idx >= total) return;
    int l = idx & 63;
    int s = (idx >> 6) % S;
    int j = idx / (64 * S);
    int col = j * 16 + (l & 15);
    int kbase = s * 32 + (l >> 4) * 8;
    int ob = ((j * S + s) * 64 + l) * 8;
    #pragma unroll
    for (int i = 0; i < 8; ++i) {
        float w = W[(size_t)(kbase + i) * DD + col];
        unsigned short h = f2bf(w);
        hi[ob + i] = h;
        lo[ob + i] = f2bf(w - bf2f(h));
    }
}

// ---- phase 2: fused GEMM1+GEMM2+multiply+split-bitmask segment reduce ----
// one 64-row tile per block; region (32KB): A_hi(8K) -> F1_hi(16K) -> SM f32(32K)
// XCD-aware bijective tile swizzle (T1): contiguous tile ranges -> one XCD's
// L2, so out-writes / nodes-rereads of neighboring segments stay L2-local.
__launch_bounds__(256, 4)
__global__ void edge_mfma_kernel(const float* __restrict__ nodes,
                                 const unsigned short* __restrict__ edgesS,
                                 const unsigned* __restrict__ sorted_nt,
                                 const unsigned* __restrict__ sorted_ns,
                                 const unsigned* __restrict__ ends,
                                 const unsigned short* __restrict__ W1h,
                                 const unsigned short* __restrict__ W1l,
                                 const unsigned short* __restrict__ W2h,
                                 const unsigned short* __restrict__ W2l,
                                 const float* __restrict__ b1,
                                 const float* __restrict__ b2,
                                 float* __restrict__ out,
                                 float* __restrict__ bpart,
                                 unsigned* __restrict__ bnode,
                                 int E) {
    __shared__ unsigned short region[16384];     // 32 KB, aliased
    __shared__ float comm[128];                  // mid-boundary partial handoff
    float* SM = reinterpret_cast<float*>(region);

    // ---- bijective XCD swizzle (m204 form; nwg % 8 != 0 safe) ----
    const int nwg = gridDim.x;
    const int q = nwg >> 3, rm = nwg & 7;
    const int bid = blockIdx.x;
    const int xcd = bid & 7, ii = bid >> 3;
    const int tp = (xcd < rm ? xcd * (q + 1)
                             : rm * (q + 1) + (xcd - rm) * q) + ii;

    const int t = threadIdx.x;
    const int tlo = tp * BM;

    // per-lane start-node ids (every wave holds ns[0..63] across its lanes)
    unsigned ns_reg = (tlo + (t & 63) < E) ? sorted_ns[tlo + (t & 63)] : SENT;

    // ---- stage A: straight copy of pre-swizzled bf16 tile (8KB) ----
    {
        const bf16x8* src = reinterpret_cast<const bf16x8*>(edgesS + (size_t)tlo * FF);
        bf16x8* dst = reinterpret_cast<bf16x8*>(region);
        dst[t]       = src[t];
        dst[256 + t] = src[256 + t];
    }
    __syncthreads();   // B1: A visible

    const int lane = t & 63, wave = t >> 6;
    const int wrow = wave * 16;
    const int lr = lane & 15, lg = lane >> 4;
    const f32x4 zero4 = { 0.f, 0.f, 0.f, 0.f };

    // ---- GEMM1 A-fragments ----
    bf16x8 a1[2];
    #pragma unroll
    for (int s = 0; s < 2; ++s) {
        int row = wrow + lr;
        a1[s] = *reinterpret_cast<const bf16x8*>(
            region + row * FF + (((s * 4 + lg) ^ (row & 7)) * 8));
    }
    __syncthreads();   // B2: A reads done -> F1 may overwrite region

    // ---- GEMM1: A_hi x (W1h + W1l), W from L2, loads grouped per j ----
    f32x4 acc1[8];
    #pragma unroll
    for (int j = 0; j < 8; ++j) acc1[j] = zero4;
    #pragma unroll
    for (int j = 0; j < 8; ++j) {
        bf16x8 wh[2], wl[2];
        #pragma unroll
        for (int s = 0; s < 2; ++s) {
            wh[s] = *reinterpret_cast<const bf16x8*>(W1h + ((size_t)((j * 2 + s) * 64 + lane)) * 8);
            wl[s] = *reinterpret_cast<const bf16x8*>(W1l + ((size_t)((j * 2 + s) * 64 + lane)) * 8);
        }
        #pragma unroll
        for (int s = 0; s < 2; ++s) {
            acc1[j] = __builtin_amdgcn_mfma_f32_16x16x32_bf16(a1[s], wh[s], acc1[j], 0, 0, 0);
            acc1[j] = __builtin_amdgcn_mfma_f32_16x16x32_bf16(a1[s], wl[s], acc1[j], 0, 0, 0);
        }
    }

    // ---- epilogue1: bias + ssp -> F1 hi (overlays A), &15 swizzle ----
    #pragma unroll
    for (int j = 0; j < 8; ++j) {
        int col = j * 16 + lr;
        float bv = b1[col];
        int gc = col >> 3, ci = col & 7;
        #pragma unroll
        for (int r = 0; r < 4; ++r) {
            int row = wrow + lg * 4 + r;
            region[row * DD + ((gc ^ (row & 15)) * 8 + ci)] =
                f2bf(ssp_f(acc1[j][r] + bv));
        }
    }
    __syncthreads();   // B3: F1 visible

    // ---- GEMM2 A-fragments from F1 ----
    bf16x8 a2[4];
    #pragma unroll
    for (int s = 0; s < 4; ++s) {
        int row = wrow + lr;
        a2[s] = *reinterpret_cast<const bf16x8*>(
            region + row * DD + (((s * 4 + lg) ^ (row & 15)) * 8));
    }
    __syncthreads();   // B4: F1 reads done -> SM may overwrite region

    // ---- issue gathered node-row loads (consumed after GEMM2) ----
    float4 nv[8];
    const float4* n4 = reinterpret_cast<const float4*>(nodes);
    #pragma unroll
    for (int it = 0; it < 8; ++it) {
        int idx = it * 256 + t;
        int row = idx >> 5, c4 = idx & 31;
        unsigned nt_ = (tlo + row < E) ? sorted_nt[tlo + row] : 0u;
        nv[it] = n4[(size_t)nt_ * 32 + c4];
    }

    // ---- GEMM2: F_hi x (W2h + W2l), W from L2, loads grouped per j ----
    f32x4 acc2[8];
    #pragma unroll
    for (int j = 0; j < 8; ++j) acc2[j] = zero4;
    #pragma unroll
    for (int j = 0; j < 8; ++j) {
        bf16x8 wh[4], wl[4];
        #pragma unroll
        for (int s = 0; s < 4; ++s) {
            wh[s] = *reinterpret_cast<const bf16x8*>(W2h + ((size_t)((j * 4 + s) * 64 + lane)) * 8);
            wl[s] = *reinterpret_cast<const bf16x8*>(W2l + ((size_t)((j * 4 + s) * 64 + lane)) * 8);
        }
        #pragma unroll
        for (int s = 0; s < 4; ++s) {
            acc2[j] = __builtin_amdgcn_mfma_f32_16x16x32_bf16(a2[s], wh[s], acc2[j], 0, 0, 0);
            acc2[j] = __builtin_amdgcn_mfma_f32_16x16x32_bf16(a2[s], wl[s], acc2[j], 0, 0, 0);
        }
    }

    // ---- epilogue2: filt = ssp(acc2 + b2) -> SM (f32, swizzled) ----
    #pragma unroll
    for (int j = 0; j < 8; ++j) {
        int col = j * 16 + lr;
        float bv = b2[col];
        #pragma unroll
        for (int r = 0; r < 4; ++r) {
            int row = wrow + lg * 4 + r;
            SM[row * DD + (col ^ ((row & 7) << 2))] = ssp_f(acc2[j][r] + bv);
        }
    }
    __syncthreads();   // B5: SM ready

    // ---- multiply: SM[row] *= nodes[nt[row]] (nv already in regs) ----
    #pragma unroll
    for (int it = 0; it < 8; ++it) {
        int idx = it * 256 + t;
        int row = idx >> 5, c4 = idx & 31;
        int foff = row * DD + ((c4 * 4) ^ ((row & 7) << 2));
        float4 mv = *reinterpret_cast<float4*>(SM + foff);
        mv.x *= nv[it].x; mv.y *= nv[it].y; mv.z *= nv[it].z; mv.w *= nv[it].w;
        *reinterpret_cast<float4*>(SM + foff) = mv;
    }
    __syncthreads();   // B6: messages ready

    // ---- split-bitmask segment reduce: 256 threads = 128 cols x 2 row-halves
    {
        int pl = (lane == 0) ? 0 : lane - 1;
        unsigned prevns = __shfl(ns_reg, pl);
        unsigned long long bnd = __ballot((lane > 0) && (ns_reg != prevns));

        unsigned n0  = __shfl(ns_reg, 0);
        unsigned n31 = __shfl(ns_reg, 31);
        unsigned n32 = __shfl(ns_reg, 32);
        bool cont_mid = (n31 == n32) && (n31 != SENT);
        unsigned s0 = (n0 == 0u) ? 0u : ends[n0 - 1];
        bool contFirst = (s0 < (unsigned)tlo);
        bool spans0 = (n0 == n31);

        const int y = t >> 7;           // row-half owner
        const int col = t & 127;
        const int rbeg = y * 32;

        float firstacc = 0.f;
        bool firstpend = false;

        float acc = 0.f;
        int segstart = rbeg;
        bool pend = (y == 1) && cont_mid;   // leading seg continues from lower half
        #pragma unroll 1
        for (int r = rbeg; r < rbeg + 32; ++r) {
            if (r > rbeg && ((bnd >> r) & 1ull)) {
                unsigned node = __shfl(ns_reg, segstart);
                if (pend) {
                    firstacc = acc; firstpend = true; pend = false;
                } else if (node != SENT) {
                    if (segstart == 0 && contFirst)
                        bpart[(size_t)tp * DD + col] = acc;
                    else
                        out[(size_t)node * DD + col] = nodes[(size_t)node * DD + col] + acc;
                }
                acc = 0.f; segstart = r;
            }
            acc += SM[r * DD + (col ^ ((r & 7) << 2))];
        }
        // trailing segment of this row-half
        {
            unsigned node = __shfl(ns_reg, segstart);
            if (y == 0 && cont_mid) {
                comm[col] = acc;                 // pass partial to upper half
            } else if (pend) {
                firstacc = acc; firstpend = true;
            } else if (node != SENT) {
                if (segstart == 0 && contFirst)
                    bpart[(size_t)tp * DD + col] = acc;
                else
                    out[(size_t)node * DD + col] = nodes[(size_t)node * DD + col] + acc;
            }
        }
        if (t == 0) bnode[tp] = contFirst ? n0 : SENT;
        __syncthreads();   // comm visible

        if (y == 1 && firstpend) {
            float total = comm[col] + firstacc;
            if (spans0 && contFirst)
                bpart[(size_t)tp * DD + col] = total;
            else
                out[(size_t)n31 * DD + col] = nodes[(size_t)n31 * DD + col] + total;
        }
    }
}

// ---- fixup: add cross-tile boundary partials ----
__global__ void fixup_bpart_kernel(const float* __restrict__ bpart,
                                   const unsigned* __restrict__ bnode,
                                   float* __restrict__ out, int NT) {
    int ti = blockIdx.x * 2 + (threadIdx.x >> 7);
    if (ti >= NT) return;
    unsigned n = bnode[ti];
    if (n == SENT) return;
    int c = threadIdx.x & 127;
    atomicAdd(&out[(size_t)n * DD + c], bpart[(size_t)ti * DD + c]);
}

// ---- nodes with zero out-edges: out = nodes ----
__global__ void copy_empty_kernel(const unsigned* __restrict__ counts,
                                  const float4* __restrict__ nodes4,
                                  float4* __restrict__ out4, int N) {
    int n = blockIdx.x * 8 + (threadIdx.x >> 5);
    if (n >= N) return;
    if (counts[n] != 0u) return;
    int d4 = threadIdx.x & 31;
    out4[(size_t)n * 32 + d4] = nodes4[(size_t)n * 32 + d4];
}

// ---- fallback: fused atomic kernel (used only if ws too small) ----
__launch_bounds__(256, 2)
__global__ void edge_fused_atomic_kernel(const float* __restrict__ nodes,
                                         const float* __restrict__ edges,
                                         const int*   __restrict__ eidx,
                                         const float* __restrict__ W1,
                                         const float* __restrict__ b1,
                                         const float* __restrict__ W2,
                                         const float* __restrict__ b2,
                                         float* __restrict__ out, int E) {
    int e = blockIdx.x * 256 + threadIdx.x;
    if (e >= E) return;
    int ns = eidx[2 * e + 0];
    int nt = eidx[2 * e + 1];

    float h1[DD];
    #pragma unroll
    for (int d = 0; d < DD; ++d) h1[d] = b1[d];
    const float4* ev4 = reinterpret_cast<const float4*>(edges) + (size_t)e * (FF / 4);
    #pragma unroll 1
    for (int f4 = 0; f4 < FF / 4; ++f4) {
        float4 ev = ev4[f4];
        const float* w0 = W1 + (size_t)(f4 * 4) * DD;
        #pragma unroll
        for (int d = 0; d < DD; ++d) h1[d] = fmaf(ev.x, w0[d], h1[d]);
        #pragma unroll
        for (int d = 0; d < DD; ++d) h1[d] = fmaf(ev.y, w0[DD + d], h1[d]);
        #pragma unroll
        for (int d = 0; d < DD; ++d) h1[d] = fmaf(ev.z, w0[2 * DD + d], h1[d]);
        #pragma unroll
        for (int d = 0; d < DD; ++d) h1[d] = fmaf(ev.w, w0[3 * DD + d], h1[d]);
    }
    #pragma unroll
    for (int d = 0; d < DD; ++d) h1[d] = ssp_f(h1[d]);

    const float* nrow = nodes + (size_t)nt * DD;
    float*       orow = out   + (size_t)ns * DD;
    #pragma unroll 1
    for (int c = 0; c < 2; ++c) {
        const int base = c * 64;
        float h2[64];
        #pragma unroll
        for (int j = 0; j < 64; ++j) h2[j] = b2[base + j];
        #pragma unroll
        for (int k = 0; k < DD; ++k) {
            float hk = h1[k];
            const float* w = W2 + (size_t)k * DD + base;
            #pragma unroll
            for (int j = 0; j < 64; ++j) h2[j] = fmaf(hk, w[j], h2[j]);
        }
        #pragma unroll
        for (int j = 0; j < 64; ++j) {
            float m = ssp_f(h2[j]) * nrow[base + j];
            __hip_atomic_fetch_add(&orow[base + j], m,
                                   __ATOMIC_RELAXED, __HIP_MEMORY_SCOPE_AGENT);
        }
    }
}

extern "C" void kernel_launch(void* const* d_in, const int* in_sizes, int n_in,
                              void* d_out, int out_size, void* d_ws, size_t ws_size,
                              hipStream_t stream) {
    const float* nodes = (const float*)d_in[0];
    const float* edges = (const float*)d_in[1];
    const int*   eidx  = (const int*)  d_in[2];
    const float* W1    = (const float*)d_in[3];
    const float* b1    = (const float*)d_in[4];
    const float* W2    = (const float*)d_in[5];
    const float* b2    = (const float*)d_in[6];
    float* out = (float*)d_out;

    int ND = in_sizes[0];         // N*D
    int N  = ND / DD;             // 100000
    int E  = in_sizes[1] / FF;    // 600000
    int NT = (E + BM - 1) / BM;   // 64-row tiles

    // ---- workspace layout ----
    int nb = (N + 255) / 256;
    uintptr_t base = (uintptr_t)d_ws;
    uintptr_t p = base;
    unsigned* counts    = (unsigned*)p;  p += (size_t)N * 4;
    unsigned* cursor    = (unsigned*)p;  p += (size_t)N * 4;
    unsigned* bsums     = (unsigned*)p;  p += (size_t)nb * 4;
    unsigned* sorted_nt = (unsigned*)p;  p += (size_t)E * 4;
    unsigned* sorted_ns = (unsigned*)p;  p += (size_t)E * 4;
    p = (p + 255) & ~(uintptr_t)255;
    unsigned short* W1h = (unsigned short*)p;  p += (size_t)FF * DD * 2;
    unsigned short* W1l = (unsigned short*)p;  p += (size_t)FF * DD * 2;
    unsigned short* W2h = (unsigned short*)p;  p += (size_t)DD * DD * 2;
    unsigned short* W2l = (unsigned short*)p;  p += (size_t)DD * DD * 2;
    unsigned* bnode     = (unsigned*)p;  p += (size_t)NT * 4;
    p = (p + 255) & ~(uintptr_t)255;
    float* bpart        = (float*)p;     p += (size_t)NT * DD * 4;
    p = (p + 255) & ~(uintptr_t)255;
    unsigned short* edgesS = (unsigned short*)p;
    p += (size_t)NT * BM * FF * 2;       // pre-gathered bf16 edge tiles (~77MB)

    if ((size_t)(p - base) > ws_size) {
        copy_nodes_kernel<<<dim3(1024), dim3(256), 0, stream>>>(
            (const float4*)nodes, (float4*)out, ND / 4);
        edge_fused_atomic_kernel<<<dim3((E + 255) / 256), dim3(256), 0, stream>>>(
            nodes, edges, eidx, W1, b1, W2, b2, out, E);
        return;
    }

    // ---- prep weight fragments (bf16 split, MFMA B layout) ----
    prep_w_kernel<<<dim3(4), dim3(256), 0, stream>>>(W1, FF, W1h, W1l);
    prep_w_kernel<<<dim3(8), dim3(256), 0, stream>>>(W2, DD, W2h, W2l);

    // ---- counting sort by start node; move+convert edge rows in-pass ----
    zero_u32_kernel<<<dim3(256), dim3(256), 0, stream>>>(counts, N);
    hist_kernel<<<dim3((E + 255) / 256), dim3(256), 0, stream>>>(eidx, counts, E);
    scan1_kernel<<<dim3(nb), dim3(256), 0, stream>>>(counts, cursor, bsums, N);
    scan2_kernel<<<dim3(1), dim3(512), 0, stream>>>(bsums, nb);
    scan3_kernel<<<dim3(nb), dim3(256), 0, stream>>>(cursor, bsums, N);
    scatter_move_kernel<<<dim3((E + 255) / 256), dim3(256), 0, stream>>>(
        eidx, edges, cursor, edgesS, sorted_nt, sorted_ns, E);

    // ---- zero-edge nodes: out = nodes ----
    copy_empty_kernel<<<dim3((N + 7) / 8), dim3(256), 0, stream>>>(
        counts, (const float4*)nodes, (float4*)out, N);

    // ---- fused edge kernel (one tile per block, XCD-swizzled) ----
    edge_mfma_kernel<<<dim3(NT), dim3(256), 0, stream>>>(
        nodes, edgesS, sorted_nt, sorted_ns, cursor,
        W1h, W1l, W2h, W2l, b1, b2, out, bpart, bnode, E);

    // ---- cross-tile boundary fixup ----
    fixup_bpart_kernel<<<dim3((NT + 1) / 2), dim3(256), 0, stream>>>(
        bpart, bnode, out, NT);
}